// Round 14
// baseline (144.300 us; speedup 1.0000x reference)
//
#include <hip/hip_runtime.h>
#include <hip/hip_bf16.h>

#define BN_TOTAL   131072      // B*N
#define T_DIM      96
#define E_NUM      8
#define H_DIM      128
#define CAP        131072
#define PTHRESH    0.05f
#define NBLK       128         // expert blocks per expert (1024 total = 4/CU)

typedef _Float16 f16x8 __attribute__((ext_vector_type(8)));
typedef _Float16 f16x4 __attribute__((ext_vector_type(4)));
typedef float    f32x4 __attribute__((ext_vector_type(4)));

// ---- workspace layout (bytes) ----
#define OFF_TOK    1024
#define OFF_SCALE  (OFF_TOK   + E_NUM * CAP * 4)
#define OFF_MASK   (OFF_SCALE + E_NUM * CAP * 4)
#define OFF_COEF   (OFF_MASK  + BN_TOTAL * 4)
#define OFF_YBUF   (OFF_COEF  + BN_TOTAL * 4)
#define OFF_XH     (OFF_YBUF + 2 * BN_TOTAL * T_DIM * 2)
#define OFF_W1T    (OFF_XH   + BN_TOTAL * T_DIM * 2)
#define OFF_W2T    (OFF_W1T  + E_NUM * H_DIM * T_DIM * 2)
#define WS_NEED    ((size_t)OFF_YBUF + (size_t)2 * BN_TOTAL * T_DIM * 4)

// toklist entries PACKED: (token<<1)|k ; ybh row id == packed value (< 2*BN).

__global__ void zero_cnt_kernel(int* __restrict__ cnt) {   // non-gather fallback only
    if (threadIdx.x < E_NUM) cnt[threadIdx.x] = 0;
}

// ---- prep: LDS-tiled transpose to f16; block 0 also zeroes cnt[] ----
__global__ __launch_bounds__(256) void prep_kernel(
    const float* __restrict__ W1, const float* __restrict__ W2,
    _Float16* __restrict__ w1T, _Float16* __restrict__ w2T,
    int* __restrict__ cnt)
{
    __shared__ _Float16 tile[128 * 136];
    const int tid = threadIdx.x;
    if (blockIdx.x == 0 && tid < E_NUM) cnt[tid] = 0;
    const bool isW1 = blockIdx.x < 8;
    const int e = blockIdx.x & 7;
    const int R = isW1 ? T_DIM : H_DIM;     // src rows
    const int C = isW1 ? H_DIM : T_DIM;     // src cols
    const int S = isW1 ? 104 : 136;         // LDS row stride (f16)
    const float* src = (isW1 ? W1 : W2) + (size_t)e * T_DIM * H_DIM;
    _Float16* dst = (isW1 ? w1T : w2T) + (size_t)e * T_DIM * H_DIM;

    const int nb = (R >> 2) * (C >> 2);
    for (int b = tid; b < nb; b += 256) {
        const int r4 = b / (C >> 2), c4 = b % (C >> 2);
#pragma unroll
        for (int i = 0; i < 4; ++i) {
            const float4 v = *reinterpret_cast<const float4*>(src + (size_t)(4 * r4 + i) * C + 4 * c4);
            tile[(4 * c4 + 0) * S + 4 * r4 + i] = (_Float16)v.x;
            tile[(4 * c4 + 1) * S + 4 * r4 + i] = (_Float16)v.y;
            tile[(4 * c4 + 2) * S + 4 * r4 + i] = (_Float16)v.z;
            tile[(4 * c4 + 3) * S + 4 * r4 + i] = (_Float16)v.w;
        }
    }
    __syncthreads();
    const int chunks = C * (R >> 3);
    for (int q = tid; q < chunks; q += 256) {
        const int cr = q / (R >> 3), k = q % (R >> 3);
        *reinterpret_cast<f16x8*>(dst + (size_t)cr * R + 8 * k) =
            *reinterpret_cast<const f16x8*>(&tile[cr * S + 8 * k]);
    }
}

// ---- gate: 1024-thread blocks; atomic chain overlapped with global writes ----
template<bool GATHER>
__global__ __launch_bounds__(1024) void gate_kernel(
    const float* __restrict__ x, const float* __restrict__ Wg,
    const float* __restrict__ bg, const float* __restrict__ rs_p,
    float* __restrict__ mixed, float* __restrict__ util,
    int* __restrict__ cnt, int* __restrict__ toklist, float* __restrict__ scalelist,
    int* __restrict__ maskbuf, float* __restrict__ coefbuf, _Float16* __restrict__ xh)
{
    __shared__ float wg_s[E_NUM][T_DIM];
    __shared__ float bg_s[E_NUM];
    __shared__ int wcnt[16][E_NUM];
    __shared__ int wbase[16][E_NUM];

    const int tid = threadIdx.x;
    for (int i = tid; i < E_NUM * T_DIM; i += 1024) wg_s[i / T_DIM][i % T_DIM] = Wg[i];
    if (tid < E_NUM) bg_s[tid] = bg[tid];
    __syncthreads();

    const int g   = tid >> 2;            // token slot 0..255
    const int sub = tid & 3;             // dim quarter
    const int token = blockIdx.x * 256 + g;
    const float* xr_f = x + (size_t)token * T_DIM + sub * 24;

    float4 xv[6];
#pragma unroll
    for (int i = 0; i < 6; ++i) xv[i] = reinterpret_cast<const float4*>(xr_f)[i];

    float logit[E_NUM];
#pragma unroll
    for (int e = 0; e < E_NUM; ++e) logit[e] = 0.0f;
#pragma unroll
    for (int i = 0; i < 6; ++i) {
#pragma unroll
        for (int e = 0; e < E_NUM; ++e) {
            const float4 wv = *reinterpret_cast<const float4*>(&wg_s[e][sub * 24 + 4 * i]);
            logit[e] = fmaf(xv[i].x, wv.x, logit[e]);
            logit[e] = fmaf(xv[i].y, wv.y, logit[e]);
            logit[e] = fmaf(xv[i].z, wv.z, logit[e]);
            logit[e] = fmaf(xv[i].w, wv.w, logit[e]);
        }
    }
#pragma unroll
    for (int e = 0; e < E_NUM; ++e) {
        logit[e] += __shfl_xor(logit[e], 1);
        logit[e] += __shfl_xor(logit[e], 2);
        logit[e] = (logit[e] + bg_s[e]) / 10.0f;
    }

    float mx = logit[0];
#pragma unroll
    for (int e = 1; e < E_NUM; ++e) mx = fmaxf(mx, logit[e]);
    float p[E_NUM]; float s = 0.0f;
#pragma unroll
    for (int e = 0; e < E_NUM; ++e) { p[e] = __expf(logit[e] - mx); s += p[e]; }
    const float inv_s = 1.0f / s;
#pragma unroll
    for (int e = 0; e < E_NUM; ++e) p[e] *= inv_s;

    int i0 = 0; float p0 = p[0];
#pragma unroll
    for (int e = 1; e < E_NUM; ++e) { if (p[e] > p0) { p0 = p[e]; i0 = e; } }
    int i1 = -1; float p1 = -1.0f;
#pragma unroll
    for (int e = 0; e < E_NUM; ++e) { if (e != i0 && p[e] > p1) { p1 = p[e]; i1 = e; } }

    const float denom0 = p0 + p1 + 1e-12f;
    const float w0 = p0 / denom0, w1 = p1 / denom0;
    const bool m0 = (w0 >= PTHRESH), m1 = (w1 >= PTHRESH);
    const float sumw = w0 + w1;
    const float denom1 = fmaxf(sumw, 1e-12f);
    const float wn0 = w0 / denom1, wn1 = w1 / denom1;
    const float rs = *rs_p;
    const float coef = rs * (wn0 + wn1);
    const bool lead = (sub == 0);

    // ---- ballot + per-wave counts FIRST (so the atomic can issue early) ----
    const int lane = tid & 63;
    const int wv_id = tid >> 6;          // 0..15
    const unsigned long long lt = (1ULL << lane) - 1ULL;

    int wcnt_mine = 0, offA = 0, offB = 0;
#pragma unroll
    for (int e = 0; e < E_NUM; ++e) {
        const unsigned long long A = __ballot(lead && m0 && (i0 == e));
        const unsigned long long B = __ballot(lead && m1 && (i1 == e));
        const int na = __popcll(A), nb = __popcll(B);
        if (lane == e) wcnt_mine = na + nb;
        if (lead && m0 && (i0 == e)) offA = __popcll(A & lt);
        if (lead && m1 && (i1 == e)) offB = na + __popcll(B & lt);
    }
    if (lane < E_NUM) wcnt[wv_id][lane] = wcnt_mine;
    __syncthreads();

    // 8 threads issue the device-serialized atomic; result consumed AFTER the
    // overlap region below, so the chain hides under the global writes.
    int run = 0, c[16];
    if (tid < E_NUM) {
        int tot = 0;
#pragma unroll
        for (int w = 0; w < 16; ++w) { c[w] = wcnt[w][tid]; tot += c[w]; }
        run = atomicAdd(&cnt[tid], tot);          // issued; result needed later
    }

    // ---- overlap region: all waves stream xh/util/coef/mask ----
    if (GATHER) {
        _Float16* xr = xh + (size_t)token * T_DIM + sub * 24;
#pragma unroll
        for (int i = 0; i < 6; ++i) {
            f16x4 h4;
            h4[0] = (_Float16)xv[i].x; h4[1] = (_Float16)xv[i].y;
            h4[2] = (_Float16)xv[i].z; h4[3] = (_Float16)xv[i].w;
            reinterpret_cast<f16x4*>(xr)[i] = h4;
        }
        if (lead) { coefbuf[token] = coef; maskbuf[token] = (m0 ? 1 : 0) | (m1 ? 2 : 0); }
    } else {
        float* mr = mixed + (size_t)token * T_DIM + sub * 24;
#pragma unroll
        for (int i = 0; i < 6; ++i)
            reinterpret_cast<float4*>(mr)[i] =
                make_float4(coef * xv[i].x, coef * xv[i].y, coef * xv[i].z, coef * xv[i].w);
    }
    if (lead) {
        float u[E_NUM];
#pragma unroll
        for (int e = 0; e < E_NUM; ++e)
            u[e] = (((e == i0) && m0) || ((e == i1) && m1)) ? 1.0f : 0.0f;
        float4* u4 = reinterpret_cast<float4*>(util + (size_t)token * E_NUM);
        u4[0] = make_float4(u[0], u[1], u[2], u[3]);
        u4[1] = make_float4(u[4], u[5], u[6], u[7]);
    }

    // consume the atomic result, publish wave bases
    if (tid < E_NUM) {
#pragma unroll
        for (int w = 0; w < 16; ++w) { wbase[w][tid] = run; run += c[w]; }
    }
    __syncthreads();

    if (lead && m0) {
        const int pos = wbase[wv_id][i0] + offA;
        toklist[i0 * CAP + pos] = (token << 1);
        scalelist[i0 * CAP + pos] = rs * wn0;
    }
    if (lead && m1) {
        const int pos = wbase[wv_id][i1] + offB;
        toklist[i1 * CAP + pos] = (token << 1) | 1;
        scalelist[i1 * CAP + pos] = rs * wn1;
    }
}

// ---------------- MFMA expert kernel ----------------
// r13 evidence: VGPR_Count=96 -> weights are L2-reloads regardless of the
// (256,2) budget. So stop paying for it: (256,4) + NBLK=128 -> 4 blocks/CU,
// 16 waves/CU, double latency hiding. LDS 34.8KB x4 = 139KB <= 160KB.
template<bool GATHER>
__global__ __launch_bounds__(256, 4) void expert_kernel(
    const float* __restrict__ x, const _Float16* __restrict__ xh,
    const float* __restrict__ W1, const float* __restrict__ b1,
    const float* __restrict__ W2, const float* __restrict__ b2,
    const _Float16* __restrict__ w1T, const _Float16* __restrict__ w2T,
    float* __restrict__ mixed, _Float16* __restrict__ ybh,
    const int* __restrict__ cnt, const int* __restrict__ toklist,
    const float* __restrict__ scalelist)
{
    __shared__ __align__(16) _Float16 Hs[2][64 * 136];

    const int e = blockIdx.y;
    const int count = cnt[e];
    if ((int)blockIdx.x * 64 >= count) return;

    const int tid  = threadIdx.x;
    const int w    = tid >> 6;
    const int lane = tid & 63;
    const int lm   = lane & 15;
    const int lg4  = lane >> 4;
    const int mhalf = w & 1;
    const int nhalf = w >> 1;

    const int*   tl = toklist   + (size_t)e * CAP;
    const float* sl = scalelist + (size_t)e * CAP;

    f16x8 w1f[3][4];
    {
        const _Float16* w1e = w1T + (size_t)e * H_DIM * T_DIM;
        const float*    gW1 = W1  + (size_t)e * T_DIM * H_DIM;
#pragma unroll
        for (int ks = 0; ks < 3; ++ks)
#pragma unroll
            for (int n = 0; n < 4; ++n) {
                const int h = nhalf * 64 + n * 16 + lm;
                if (GATHER) {
                    w1f[ks][n] = *reinterpret_cast<const f16x8*>(
                        w1e + (size_t)h * T_DIM + ks * 32 + lg4 * 8);
                } else {
                    f16x8 v;
#pragma unroll
                    for (int j = 0; j < 8; ++j)
                        v[j] = (_Float16)gW1[(size_t)(ks * 32 + lg4 * 8 + j) * H_DIM + h];
                    w1f[ks][n] = v;
                }
            }
    }
    f16x8 w2f[4][3];
    {
        const _Float16* w2e = w2T + (size_t)e * H_DIM * T_DIM;
        const float*    gW2 = W2  + (size_t)e * H_DIM * T_DIM;
#pragma unroll
        for (int ks = 0; ks < 4; ++ks)
#pragma unroll
            for (int n = 0; n < 3; ++n) {
                const int t = nhalf * 48 + n * 16 + lm;
                if (GATHER) {
                    w2f[ks][n] = *reinterpret_cast<const f16x8*>(
                        w2e + (size_t)t * H_DIM + ks * 32 + lg4 * 8);
                } else {
                    f16x8 v;
#pragma unroll
                    for (int j = 0; j < 8; ++j)
                        v[j] = (_Float16)gW2[(size_t)(ks * 32 + lg4 * 8 + j) * T_DIM + t];
                    w2f[ks][n] = v;
                }
            }
    }
    float4 b1v[4], b2v[3];
#pragma unroll
    for (int n = 0; n < 4; ++n)
        b1v[n] = *reinterpret_cast<const float4*>(b1 + e * H_DIM + nhalf * 64 + n * 16 + lg4 * 4);
#pragma unroll
    for (int n = 0; n < 3; ++n)
        b2v[n] = *reinterpret_cast<const float4*>(b2 + e * T_DIM + nhalf * 48 + n * 16 + lg4 * 4);

    int buf = 0;
    for (int t0 = blockIdx.x * 64; t0 < count; t0 += NBLK * 64) {
        const int nt = min(64, count - t0);

        int packedi[2]; float sci[2]; bool val[2]; int rowi[2];
#pragma unroll
        for (int mt = 0; mt < 2; ++mt) {
            const int slot = (mhalf * 2 + mt) * 16 + lm;
            val[mt] = slot < nt;
            const int gi = t0 + (val[mt] ? slot : 0);
            packedi[mt] = tl[gi];
            rowi[mt] = packedi[mt] >> 1;
            sci[mt] = sl[gi];
        }

        f16x8 xf[2][3];
#pragma unroll
        for (int mt = 0; mt < 2; ++mt)
#pragma unroll
            for (int ks = 0; ks < 3; ++ks) {
                if (GATHER) {
                    xf[mt][ks] = *reinterpret_cast<const f16x8*>(
                        xh + (size_t)rowi[mt] * T_DIM + ks * 32 + lg4 * 8);
                } else {
                    const float* xp = x + (size_t)rowi[mt] * T_DIM + ks * 32 + lg4 * 8;
                    f16x8 v;
#pragma unroll
                    for (int j = 0; j < 8; ++j) v[j] = (_Float16)xp[j];
                    xf[mt][ks] = v;
                }
            }

        f32x4 acc1[2][4];
#pragma unroll
        for (int mt = 0; mt < 2; ++mt)
#pragma unroll
            for (int n = 0; n < 4; ++n) acc1[mt][n] = f32x4{0.f, 0.f, 0.f, 0.f};
#pragma unroll
        for (int ks = 0; ks < 3; ++ks)
#pragma unroll
            for (int n = 0; n < 4; ++n) {
                acc1[0][n] = __builtin_amdgcn_mfma_f32_16x16x32_f16(w1f[ks][n], xf[0][ks], acc1[0][n], 0, 0, 0);
                acc1[1][n] = __builtin_amdgcn_mfma_f32_16x16x32_f16(w1f[ks][n], xf[1][ks], acc1[1][n], 0, 0, 0);
            }

#pragma unroll
        for (int mt = 0; mt < 2; ++mt) {
            const int tok = (mhalf * 2 + mt) * 16 + lm;
#pragma unroll
            for (int n = 0; n < 4; ++n) {
                const float* bb = reinterpret_cast<const float*>(&b1v[n]);
                f16x4 hv;
#pragma unroll
                for (int r = 0; r < 4; ++r)
                    hv[r] = (_Float16)fmaxf(acc1[mt][n][r] + bb[r], 0.0f);
                *reinterpret_cast<f16x4*>(&Hs[buf][tok * 136 + nhalf * 64 + n * 16 + lg4 * 4]) = hv;
            }
        }
        __syncthreads();

        f32x4 acc2[2][3];
#pragma unroll
        for (int mt = 0; mt < 2; ++mt)
#pragma unroll
            for (int n = 0; n < 3; ++n) acc2[mt][n] = f32x4{0.f, 0.f, 0.f, 0.f};
#pragma unroll
        for (int ks = 0; ks < 4; ++ks) {
            const f16x8 hf0 = *reinterpret_cast<const f16x8*>(
                &Hs[buf][((mhalf * 2 + 0) * 16 + lm) * 136 + ks * 32 + lg4 * 8]);
            const f16x8 hf1 = *reinterpret_cast<const f16x8*>(
                &Hs[buf][((mhalf * 2 + 1) * 16 + lm) * 136 + ks * 32 + lg4 * 8]);
#pragma unroll
            for (int n = 0; n < 3; ++n) {
                acc2[0][n] = __builtin_amdgcn_mfma_f32_16x16x32_f16(w2f[ks][n], hf0, acc2[0][n], 0, 0, 0);
                acc2[1][n] = __builtin_amdgcn_mfma_f32_16x16x32_f16(w2f[ks][n], hf1, acc2[1][n], 0, 0, 0);
            }
        }

#pragma unroll
        for (int mt = 0; mt < 2; ++mt) {
            if (val[mt]) {
#pragma unroll
                for (int n = 0; n < 3; ++n) {
                    const float* bb = reinterpret_cast<const float*>(&b2v[n]);
                    f16x4 yv;
#pragma unroll
                    for (int r = 0; r < 4; ++r)
                        yv[r] = (_Float16)(sci[mt] * (acc2[mt][n][r] + bb[r]));
                    if (GATHER) {
                        *reinterpret_cast<f16x4*>(
                            ybh + (size_t)packedi[mt] * T_DIM + nhalf * 48 + n * 16 + lg4 * 4) = yv;
                    } else {
#pragma unroll
                        for (int r = 0; r < 4; ++r)
                            atomicAdd(&mixed[(size_t)(packedi[mt] >> 1) * T_DIM +
                                             nhalf * 48 + n * 16 + lg4 * 4 + r], (float)yv[r]);
                    }
                }
            }
        }
        buf ^= 1;
    }
}

// mixed[tok] = coef*xh[tok] + (mask&1 ? ybh[2t] : 0) + (mask&2 ? ybh[2t+1] : 0)
__global__ __launch_bounds__(256) void finalize_kernel(
    const _Float16* __restrict__ xh, const _Float16* __restrict__ ybh,
    const int* __restrict__ maskbuf, const float* __restrict__ coefbuf,
    float* __restrict__ mixed)
{
    const int tid = threadIdx.x;
    const int token = blockIdx.x * 32 + (tid >> 3);
    const int seg = (tid & 7) * 12;

    const float coef = coefbuf[token];
    const int mask = maskbuf[token];

    const f16x4* xs = reinterpret_cast<const f16x4*>(xh + (size_t)token * T_DIM + seg);
    float4* od = reinterpret_cast<float4*>(mixed + (size_t)token * T_DIM + seg);

    float4 r[3];
#pragma unroll
    for (int q = 0; q < 3; ++q) {
        const f16x4 xv = xs[q];
        r[q] = make_float4(coef * (float)xv[0], coef * (float)xv[1],
                           coef * (float)xv[2], coef * (float)xv[3]);
    }
    if (mask & 1) {
        const f16x4* ys = reinterpret_cast<const f16x4*>(ybh + (size_t)(2 * token) * T_DIM + seg);
#pragma unroll
        for (int q = 0; q < 3; ++q) {
            const f16x4 yv = ys[q];
            r[q].x += (float)yv[0]; r[q].y += (float)yv[1];
            r[q].z += (float)yv[2]; r[q].w += (float)yv[3];
        }
    }
    if (mask & 2) {
        const f16x4* ys = reinterpret_cast<const f16x4*>(ybh + (size_t)(2 * token + 1) * T_DIM + seg);
#pragma unroll
        for (int q = 0; q < 3; ++q) {
            const f16x4 yv = ys[q];
            r[q].x += (float)yv[0]; r[q].y += (float)yv[1];
            r[q].z += (float)yv[2]; r[q].w += (float)yv[3];
        }
    }
#pragma unroll
    for (int q = 0; q < 3; ++q) od[q] = r[q];
}

extern "C" void kernel_launch(void* const* d_in, const int* in_sizes, int n_in,
                              void* d_out, int out_size, void* d_ws, size_t ws_size,
                              hipStream_t stream)
{
    const float* x  = (const float*)d_in[0];
    const float* Wg = (const float*)d_in[1];
    const float* bg = (const float*)d_in[2];
    const float* W1 = (const float*)d_in[3];
    const float* b1 = (const float*)d_in[4];
    const float* W2 = (const float*)d_in[5];
    const float* b2 = (const float*)d_in[6];
    const float* rs = (const float*)d_in[7];

    float* mixed = (float*)d_out;
    float* util  = mixed + (size_t)BN_TOTAL * T_DIM;

    char* ws = (char*)d_ws;
    int*      cnt       = (int*)ws;
    int*      toklist   = (int*)(ws + OFF_TOK);
    float*    scalelist = (float*)(ws + OFF_SCALE);
    int*      maskbuf   = (int*)(ws + OFF_MASK);
    float*    coefbuf   = (float*)(ws + OFF_COEF);
    _Float16* ybh       = (_Float16*)(ws + OFF_YBUF);
    _Float16* xh        = (_Float16*)(ws + OFF_XH);
    _Float16* w1T       = (_Float16*)(ws + OFF_W1T);
    _Float16* w2T       = (_Float16*)(ws + OFF_W2T);

    const bool gather = (ws_size >= WS_NEED);

    if (gather) {
        prep_kernel<<<16, 256, 0, stream>>>(W1, W2, w1T, w2T, cnt);
        gate_kernel<true><<<BN_TOTAL / 256, 1024, 0, stream>>>(
            x, Wg, bg, rs, mixed, util, cnt, toklist, scalelist, maskbuf, coefbuf, xh);
        expert_kernel<true><<<dim3(NBLK, E_NUM), 256, 0, stream>>>(
            x, xh, W1, b1, W2, b2, w1T, w2T, mixed, ybh, cnt, toklist, scalelist);
        finalize_kernel<<<BN_TOTAL / 32, 256, 0, stream>>>(
            xh, ybh, maskbuf, coefbuf, mixed);
    } else {
        zero_cnt_kernel<<<1, 64, 0, stream>>>(cnt);
        gate_kernel<false><<<BN_TOTAL / 256, 1024, 0, stream>>>(
            x, Wg, bg, rs, mixed, util, cnt, toklist, scalelist, maskbuf, coefbuf, xh);
        expert_kernel<false><<<dim3(NBLK, E_NUM), 256, 0, stream>>>(
            x, xh, W1, b1, W2, b2, w1T, w2T, mixed, ybh, cnt, toklist, scalelist);
    }
}

// Round 15
// 94.752 us; speedup vs baseline: 1.5229x; 1.5229x over previous
//
#include <hip/hip_runtime.h>
#include <hip/hip_bf16.h>

#define BN_TOTAL   131072      // B*N
#define T_DIM      96
#define E_NUM      8
#define H_DIM      128
#define CAP        131072
#define PTHRESH    0.05f
#define NBLK       64          // expert blocks per expert (512 total = 2/CU)

typedef _Float16 f16x8 __attribute__((ext_vector_type(8)));
typedef _Float16 f16x4 __attribute__((ext_vector_type(4)));
typedef float    f32x4 __attribute__((ext_vector_type(4)));

// ---- workspace layout (bytes) ----
#define OFF_TOK    1024
#define OFF_SCALE  (OFF_TOK   + E_NUM * CAP * 4)
#define OFF_MASK   (OFF_SCALE + E_NUM * CAP * 4)
#define OFF_COEF   (OFF_MASK  + BN_TOTAL * 4)
#define OFF_YBUF   (OFF_COEF  + BN_TOTAL * 4)
#define OFF_XH     (OFF_YBUF + 2 * BN_TOTAL * T_DIM * 2)
#define OFF_W1T    (OFF_XH   + BN_TOTAL * T_DIM * 2)
#define OFF_W2T    (OFF_W1T  + E_NUM * H_DIM * T_DIM * 2)
#define WS_NEED    ((size_t)OFF_YBUF + (size_t)2 * BN_TOTAL * T_DIM * 4)

// toklist entries PACKED: (token<<1)|k ; ybh row id == packed value (< 2*BN).

__global__ void zero_cnt_kernel(int* __restrict__ cnt) {   // non-gather fallback only
    if (threadIdx.x < E_NUM) cnt[threadIdx.x] = 0;
}

// ---- prep: LDS-tiled transpose to f16; block 0 also zeroes cnt[] ----
__global__ __launch_bounds__(256) void prep_kernel(
    const float* __restrict__ W1, const float* __restrict__ W2,
    _Float16* __restrict__ w1T, _Float16* __restrict__ w2T,
    int* __restrict__ cnt)
{
    __shared__ _Float16 tile[128 * 136];
    const int tid = threadIdx.x;
    if (blockIdx.x == 0 && tid < E_NUM) cnt[tid] = 0;
    const bool isW1 = blockIdx.x < 8;
    const int e = blockIdx.x & 7;
    const int R = isW1 ? T_DIM : H_DIM;     // src rows
    const int C = isW1 ? H_DIM : T_DIM;     // src cols
    const int S = isW1 ? 104 : 136;         // LDS row stride (f16)
    const float* src = (isW1 ? W1 : W2) + (size_t)e * T_DIM * H_DIM;
    _Float16* dst = (isW1 ? w1T : w2T) + (size_t)e * T_DIM * H_DIM;

    const int nb = (R >> 2) * (C >> 2);
    for (int b = tid; b < nb; b += 256) {
        const int r4 = b / (C >> 2), c4 = b % (C >> 2);
#pragma unroll
        for (int i = 0; i < 4; ++i) {
            const float4 v = *reinterpret_cast<const float4*>(src + (size_t)(4 * r4 + i) * C + 4 * c4);
            tile[(4 * c4 + 0) * S + 4 * r4 + i] = (_Float16)v.x;
            tile[(4 * c4 + 1) * S + 4 * r4 + i] = (_Float16)v.y;
            tile[(4 * c4 + 2) * S + 4 * r4 + i] = (_Float16)v.z;
            tile[(4 * c4 + 3) * S + 4 * r4 + i] = (_Float16)v.w;
        }
    }
    __syncthreads();
    const int chunks = C * (R >> 3);
    for (int q = tid; q < chunks; q += 256) {
        const int cr = q / (R >> 3), k = q % (R >> 3);
        *reinterpret_cast<f16x8*>(dst + (size_t)cr * R + 8 * k) =
            *reinterpret_cast<const f16x8*>(&tile[cr * S + 8 * k]);
    }
}

// ---- gate: 1024-thread blocks; atomic chain overlapped with global writes ----
template<bool GATHER>
__global__ __launch_bounds__(1024) void gate_kernel(
    const float* __restrict__ x, const float* __restrict__ Wg,
    const float* __restrict__ bg, const float* __restrict__ rs_p,
    float* __restrict__ mixed, float* __restrict__ util,
    int* __restrict__ cnt, int* __restrict__ toklist, float* __restrict__ scalelist,
    int* __restrict__ maskbuf, float* __restrict__ coefbuf, _Float16* __restrict__ xh)
{
    __shared__ float wg_s[E_NUM][T_DIM];
    __shared__ float bg_s[E_NUM];
    __shared__ int wcnt[16][E_NUM];
    __shared__ int wbase[16][E_NUM];

    const int tid = threadIdx.x;
    for (int i = tid; i < E_NUM * T_DIM; i += 1024) wg_s[i / T_DIM][i % T_DIM] = Wg[i];
    if (tid < E_NUM) bg_s[tid] = bg[tid];
    __syncthreads();

    const int g   = tid >> 2;            // token slot 0..255
    const int sub = tid & 3;             // dim quarter
    const int token = blockIdx.x * 256 + g;
    const float* xr_f = x + (size_t)token * T_DIM + sub * 24;

    float4 xv[6];
#pragma unroll
    for (int i = 0; i < 6; ++i) xv[i] = reinterpret_cast<const float4*>(xr_f)[i];

    float logit[E_NUM];
#pragma unroll
    for (int e = 0; e < E_NUM; ++e) logit[e] = 0.0f;
#pragma unroll
    for (int i = 0; i < 6; ++i) {
#pragma unroll
        for (int e = 0; e < E_NUM; ++e) {
            const float4 wv = *reinterpret_cast<const float4*>(&wg_s[e][sub * 24 + 4 * i]);
            logit[e] = fmaf(xv[i].x, wv.x, logit[e]);
            logit[e] = fmaf(xv[i].y, wv.y, logit[e]);
            logit[e] = fmaf(xv[i].z, wv.z, logit[e]);
            logit[e] = fmaf(xv[i].w, wv.w, logit[e]);
        }
    }
#pragma unroll
    for (int e = 0; e < E_NUM; ++e) {
        logit[e] += __shfl_xor(logit[e], 1);
        logit[e] += __shfl_xor(logit[e], 2);
        logit[e] = (logit[e] + bg_s[e]) / 10.0f;
    }

    float mx = logit[0];
#pragma unroll
    for (int e = 1; e < E_NUM; ++e) mx = fmaxf(mx, logit[e]);
    float p[E_NUM]; float s = 0.0f;
#pragma unroll
    for (int e = 0; e < E_NUM; ++e) { p[e] = __expf(logit[e] - mx); s += p[e]; }
    const float inv_s = 1.0f / s;
#pragma unroll
    for (int e = 0; e < E_NUM; ++e) p[e] *= inv_s;

    int i0 = 0; float p0 = p[0];
#pragma unroll
    for (int e = 1; e < E_NUM; ++e) { if (p[e] > p0) { p0 = p[e]; i0 = e; } }
    int i1 = -1; float p1 = -1.0f;
#pragma unroll
    for (int e = 0; e < E_NUM; ++e) { if (e != i0 && p[e] > p1) { p1 = p[e]; i1 = e; } }

    const float denom0 = p0 + p1 + 1e-12f;
    const float w0 = p0 / denom0, w1 = p1 / denom0;
    const bool m0 = (w0 >= PTHRESH), m1 = (w1 >= PTHRESH);
    const float sumw = w0 + w1;
    const float denom1 = fmaxf(sumw, 1e-12f);
    const float wn0 = w0 / denom1, wn1 = w1 / denom1;
    const float rs = *rs_p;
    const float coef = rs * (wn0 + wn1);
    const bool lead = (sub == 0);

    // ---- ballot + per-wave counts FIRST (so the atomic can issue early) ----
    const int lane = tid & 63;
    const int wv_id = tid >> 6;          // 0..15
    const unsigned long long lt = (1ULL << lane) - 1ULL;

    int wcnt_mine = 0, offA = 0, offB = 0;
#pragma unroll
    for (int e = 0; e < E_NUM; ++e) {
        const unsigned long long A = __ballot(lead && m0 && (i0 == e));
        const unsigned long long B = __ballot(lead && m1 && (i1 == e));
        const int na = __popcll(A), nb = __popcll(B);
        if (lane == e) wcnt_mine = na + nb;
        if (lead && m0 && (i0 == e)) offA = __popcll(A & lt);
        if (lead && m1 && (i1 == e)) offB = na + __popcll(B & lt);
    }
    if (lane < E_NUM) wcnt[wv_id][lane] = wcnt_mine;
    __syncthreads();

    // 8 threads issue the device-serialized atomic; result consumed AFTER the
    // overlap region below, so the chain hides under the global writes.
    int run = 0, c[16];
    if (tid < E_NUM) {
        int tot = 0;
#pragma unroll
        for (int w = 0; w < 16; ++w) { c[w] = wcnt[w][tid]; tot += c[w]; }
        run = atomicAdd(&cnt[tid], tot);          // issued; result needed later
    }

    // ---- overlap region: all waves stream xh/util/coef/mask ----
    if (GATHER) {
        _Float16* xr = xh + (size_t)token * T_DIM + sub * 24;
#pragma unroll
        for (int i = 0; i < 6; ++i) {
            f16x4 h4;
            h4[0] = (_Float16)xv[i].x; h4[1] = (_Float16)xv[i].y;
            h4[2] = (_Float16)xv[i].z; h4[3] = (_Float16)xv[i].w;
            reinterpret_cast<f16x4*>(xr)[i] = h4;
        }
        if (lead) { coefbuf[token] = coef; maskbuf[token] = (m0 ? 1 : 0) | (m1 ? 2 : 0); }
    } else {
        float* mr = mixed + (size_t)token * T_DIM + sub * 24;
#pragma unroll
        for (int i = 0; i < 6; ++i)
            reinterpret_cast<float4*>(mr)[i] =
                make_float4(coef * xv[i].x, coef * xv[i].y, coef * xv[i].z, coef * xv[i].w);
    }
    if (lead) {
        float u[E_NUM];
#pragma unroll
        for (int e = 0; e < E_NUM; ++e)
            u[e] = (((e == i0) && m0) || ((e == i1) && m1)) ? 1.0f : 0.0f;
        float4* u4 = reinterpret_cast<float4*>(util + (size_t)token * E_NUM);
        u4[0] = make_float4(u[0], u[1], u[2], u[3]);
        u4[1] = make_float4(u[4], u[5], u[6], u[7]);
    }

    // consume the atomic result, publish wave bases
    if (tid < E_NUM) {
#pragma unroll
        for (int w = 0; w < 16; ++w) { wbase[w][tid] = run; run += c[w]; }
    }
    __syncthreads();

    if (lead && m0) {
        const int pos = wbase[wv_id][i0] + offA;
        toklist[i0 * CAP + pos] = (token << 1);
        scalelist[i0 * CAP + pos] = rs * wn0;
    }
    if (lead && m1) {
        const int pos = wbase[wv_id][i1] + offB;
        toklist[i1 * CAP + pos] = (token << 1) | 1;
        scalelist[i1 * CAP + pos] = rs * wn1;
    }
}

// ---------------- MFMA expert kernel ----------------
// r13/r14 evidence: at (256,2) compiler kept VGPR=96 and rematerialized all 24
// weight-fragment L2 loads per iteration (~24x400cy serialized = the 12K
// cy/iter cost); at (256,4) it spilled to scratch (165MB FETCH). Fix: keep
// (256,2), cap waves at 2 (waves_per_eu), and PIN the 24 fragments with an
// opaque asm so rematerialization is impossible. ~206 VGPRs needed < 256.
template<bool GATHER>
__global__ __launch_bounds__(256, 2) __attribute__((amdgpu_waves_per_eu(2, 2)))
void expert_kernel(
    const float* __restrict__ x, const _Float16* __restrict__ xh,
    const float* __restrict__ W1, const float* __restrict__ b1,
    const float* __restrict__ W2, const float* __restrict__ b2,
    const _Float16* __restrict__ w1T, const _Float16* __restrict__ w2T,
    float* __restrict__ mixed, _Float16* __restrict__ ybh,
    const int* __restrict__ cnt, const int* __restrict__ toklist,
    const float* __restrict__ scalelist)
{
    __shared__ __align__(16) _Float16 Hs[2][64 * 136];

    const int e = blockIdx.y;
    const int count = cnt[e];
    if ((int)blockIdx.x * 64 >= count) return;

    const int tid  = threadIdx.x;
    const int w    = tid >> 6;
    const int lane = tid & 63;
    const int lm   = lane & 15;
    const int lg4  = lane >> 4;
    const int mhalf = w & 1;
    const int nhalf = w >> 1;

    const int*   tl = toklist   + (size_t)e * CAP;
    const float* sl = scalelist + (size_t)e * CAP;

    f16x8 w1f[3][4];
    {
        const _Float16* w1e = w1T + (size_t)e * H_DIM * T_DIM;
        const float*    gW1 = W1  + (size_t)e * T_DIM * H_DIM;
#pragma unroll
        for (int ks = 0; ks < 3; ++ks)
#pragma unroll
            for (int n = 0; n < 4; ++n) {
                const int h = nhalf * 64 + n * 16 + lm;
                if (GATHER) {
                    w1f[ks][n] = *reinterpret_cast<const f16x8*>(
                        w1e + (size_t)h * T_DIM + ks * 32 + lg4 * 8);
                } else {
                    f16x8 v;
#pragma unroll
                    for (int j = 0; j < 8; ++j)
                        v[j] = (_Float16)gW1[(size_t)(ks * 32 + lg4 * 8 + j) * H_DIM + h];
                    w1f[ks][n] = v;
                }
            }
    }
    f16x8 w2f[4][3];
    {
        const _Float16* w2e = w2T + (size_t)e * H_DIM * T_DIM;
        const float*    gW2 = W2  + (size_t)e * H_DIM * T_DIM;
#pragma unroll
        for (int ks = 0; ks < 4; ++ks)
#pragma unroll
            for (int n = 0; n < 3; ++n) {
                const int t = nhalf * 48 + n * 16 + lm;
                if (GATHER) {
                    w2f[ks][n] = *reinterpret_cast<const f16x8*>(
                        w2e + (size_t)t * H_DIM + ks * 32 + lg4 * 8);
                } else {
                    f16x8 v;
#pragma unroll
                    for (int j = 0; j < 8; ++j)
                        v[j] = (_Float16)gW2[(size_t)(ks * 32 + lg4 * 8 + j) * T_DIM + t];
                    w2f[ks][n] = v;
                }
            }
    }
    // Pin all fragments: opaque asm defs cannot be rematerialized, forcing
    // true register residency across the K-loop (r13: remat; r14: spill).
#pragma unroll
    for (int ks = 0; ks < 3; ++ks)
#pragma unroll
        for (int n = 0; n < 4; ++n)
            asm volatile("" : "+v"(w1f[ks][n]));
#pragma unroll
    for (int ks = 0; ks < 4; ++ks)
#pragma unroll
        for (int n = 0; n < 3; ++n)
            asm volatile("" : "+v"(w2f[ks][n]));

    float4 b1v[4], b2v[3];
#pragma unroll
    for (int n = 0; n < 4; ++n)
        b1v[n] = *reinterpret_cast<const float4*>(b1 + e * H_DIM + nhalf * 64 + n * 16 + lg4 * 4);
#pragma unroll
    for (int n = 0; n < 3; ++n)
        b2v[n] = *reinterpret_cast<const float4*>(b2 + e * T_DIM + nhalf * 48 + n * 16 + lg4 * 4);

    int buf = 0;
    for (int t0 = blockIdx.x * 64; t0 < count; t0 += NBLK * 64) {
        const int nt = min(64, count - t0);

        int packedi[2]; float sci[2]; bool val[2]; int rowi[2];
#pragma unroll
        for (int mt = 0; mt < 2; ++mt) {
            const int slot = (mhalf * 2 + mt) * 16 + lm;
            val[mt] = slot < nt;
            const int gi = t0 + (val[mt] ? slot : 0);
            packedi[mt] = tl[gi];
            rowi[mt] = packedi[mt] >> 1;
            sci[mt] = sl[gi];
        }

        f16x8 xf[2][3];
#pragma unroll
        for (int mt = 0; mt < 2; ++mt)
#pragma unroll
            for (int ks = 0; ks < 3; ++ks) {
                if (GATHER) {
                    xf[mt][ks] = *reinterpret_cast<const f16x8*>(
                        xh + (size_t)rowi[mt] * T_DIM + ks * 32 + lg4 * 8);
                } else {
                    const float* xp = x + (size_t)rowi[mt] * T_DIM + ks * 32 + lg4 * 8;
                    f16x8 v;
#pragma unroll
                    for (int j = 0; j < 8; ++j) v[j] = (_Float16)xp[j];
                    xf[mt][ks] = v;
                }
            }

        f32x4 acc1[2][4];
#pragma unroll
        for (int mt = 0; mt < 2; ++mt)
#pragma unroll
            for (int n = 0; n < 4; ++n) acc1[mt][n] = f32x4{0.f, 0.f, 0.f, 0.f};
#pragma unroll
        for (int ks = 0; ks < 3; ++ks)
#pragma unroll
            for (int n = 0; n < 4; ++n) {
                acc1[0][n] = __builtin_amdgcn_mfma_f32_16x16x32_f16(w1f[ks][n], xf[0][ks], acc1[0][n], 0, 0, 0);
                acc1[1][n] = __builtin_amdgcn_mfma_f32_16x16x32_f16(w1f[ks][n], xf[1][ks], acc1[1][n], 0, 0, 0);
            }

#pragma unroll
        for (int mt = 0; mt < 2; ++mt) {
            const int tok = (mhalf * 2 + mt) * 16 + lm;
#pragma unroll
            for (int n = 0; n < 4; ++n) {
                const float* bb = reinterpret_cast<const float*>(&b1v[n]);
                f16x4 hv;
#pragma unroll
                for (int r = 0; r < 4; ++r)
                    hv[r] = (_Float16)fmaxf(acc1[mt][n][r] + bb[r], 0.0f);
                *reinterpret_cast<f16x4*>(&Hs[buf][tok * 136 + nhalf * 64 + n * 16 + lg4 * 4]) = hv;
            }
        }
        __syncthreads();

        f32x4 acc2[2][3];
#pragma unroll
        for (int mt = 0; mt < 2; ++mt)
#pragma unroll
            for (int n = 0; n < 3; ++n) acc2[mt][n] = f32x4{0.f, 0.f, 0.f, 0.f};
#pragma unroll
        for (int ks = 0; ks < 4; ++ks) {
            const f16x8 hf0 = *reinterpret_cast<const f16x8*>(
                &Hs[buf][((mhalf * 2 + 0) * 16 + lm) * 136 + ks * 32 + lg4 * 8]);
            const f16x8 hf1 = *reinterpret_cast<const f16x8*>(
                &Hs[buf][((mhalf * 2 + 1) * 16 + lm) * 136 + ks * 32 + lg4 * 8]);
#pragma unroll
            for (int n = 0; n < 3; ++n) {
                acc2[0][n] = __builtin_amdgcn_mfma_f32_16x16x32_f16(w2f[ks][n], hf0, acc2[0][n], 0, 0, 0);
                acc2[1][n] = __builtin_amdgcn_mfma_f32_16x16x32_f16(w2f[ks][n], hf1, acc2[1][n], 0, 0, 0);
            }
        }

#pragma unroll
        for (int mt = 0; mt < 2; ++mt) {
            if (val[mt]) {
#pragma unroll
                for (int n = 0; n < 3; ++n) {
                    const float* bb = reinterpret_cast<const float*>(&b2v[n]);
                    f16x4 yv;
#pragma unroll
                    for (int r = 0; r < 4; ++r)
                        yv[r] = (_Float16)(sci[mt] * (acc2[mt][n][r] + bb[r]));
                    if (GATHER) {
                        *reinterpret_cast<f16x4*>(
                            ybh + (size_t)packedi[mt] * T_DIM + nhalf * 48 + n * 16 + lg4 * 4) = yv;
                    } else {
#pragma unroll
                        for (int r = 0; r < 4; ++r)
                            atomicAdd(&mixed[(size_t)(packedi[mt] >> 1) * T_DIM +
                                             nhalf * 48 + n * 16 + lg4 * 4 + r], (float)yv[r]);
                    }
                }
            }
        }
        buf ^= 1;
    }
}

// mixed[tok] = coef*xh[tok] + (mask&1 ? ybh[2t] : 0) + (mask&2 ? ybh[2t+1] : 0)
__global__ __launch_bounds__(256) void finalize_kernel(
    const _Float16* __restrict__ xh, const _Float16* __restrict__ ybh,
    const int* __restrict__ maskbuf, const float* __restrict__ coefbuf,
    float* __restrict__ mixed)
{
    const int tid = threadIdx.x;
    const int token = blockIdx.x * 32 + (tid >> 3);
    const int seg = (tid & 7) * 12;

    const float coef = coefbuf[token];
    const int mask = maskbuf[token];

    const f16x4* xs = reinterpret_cast<const f16x4*>(xh + (size_t)token * T_DIM + seg);
    float4* od = reinterpret_cast<float4*>(mixed + (size_t)token * T_DIM + seg);

    float4 r[3];
#pragma unroll
    for (int q = 0; q < 3; ++q) {
        const f16x4 xv = xs[q];
        r[q] = make_float4(coef * (float)xv[0], coef * (float)xv[1],
                           coef * (float)xv[2], coef * (float)xv[3]);
    }
    if (mask & 1) {
        const f16x4* ys = reinterpret_cast<const f16x4*>(ybh + (size_t)(2 * token) * T_DIM + seg);
#pragma unroll
        for (int q = 0; q < 3; ++q) {
            const f16x4 yv = ys[q];
            r[q].x += (float)yv[0]; r[q].y += (float)yv[1];
            r[q].z += (float)yv[2]; r[q].w += (float)yv[3];
        }
    }
    if (mask & 2) {
        const f16x4* ys = reinterpret_cast<const f16x4*>(ybh + (size_t)(2 * token + 1) * T_DIM + seg);
#pragma unroll
        for (int q = 0; q < 3; ++q) {
            const f16x4 yv = ys[q];
            r[q].x += (float)yv[0]; r[q].y += (float)yv[1];
            r[q].z += (float)yv[2]; r[q].w += (float)yv[3];
        }
    }
#pragma unroll
    for (int q = 0; q < 3; ++q) od[q] = r[q];
}

extern "C" void kernel_launch(void* const* d_in, const int* in_sizes, int n_in,
                              void* d_out, int out_size, void* d_ws, size_t ws_size,
                              hipStream_t stream)
{
    const float* x  = (const float*)d_in[0];
    const float* Wg = (const float*)d_in[1];
    const float* bg = (const float*)d_in[2];
    const float* W1 = (const float*)d_in[3];
    const float* b1 = (const float*)d_in[4];
    const float* W2 = (const float*)d_in[5];
    const float* b2 = (const float*)d_in[6];
    const float* rs = (const float*)d_in[7];

    float* mixed = (float*)d_out;
    float* util  = mixed + (size_t)BN_TOTAL * T_DIM;

    char* ws = (char*)d_ws;
    int*      cnt       = (int*)ws;
    int*      toklist   = (int*)(ws + OFF_TOK);
    float*    scalelist = (float*)(ws + OFF_SCALE);
    int*      maskbuf   = (int*)(ws + OFF_MASK);
    float*    coefbuf   = (float*)(ws + OFF_COEF);
    _Float16* ybh       = (_Float16*)(ws + OFF_YBUF);
    _Float16* xh        = (_Float16*)(ws + OFF_XH);
    _Float16* w1T       = (_Float16*)(ws + OFF_W1T);
    _Float16* w2T       = (_Float16*)(ws + OFF_W2T);

    const bool gather = (ws_size >= WS_NEED);

    if (gather) {
        prep_kernel<<<16, 256, 0, stream>>>(W1, W2, w1T, w2T, cnt);
        gate_kernel<true><<<BN_TOTAL / 256, 1024, 0, stream>>>(
            x, Wg, bg, rs, mixed, util, cnt, toklist, scalelist, maskbuf, coefbuf, xh);
        expert_kernel<true><<<dim3(NBLK, E_NUM), 256, 0, stream>>>(
            x, xh, W1, b1, W2, b2, w1T, w2T, mixed, ybh, cnt, toklist, scalelist);
        finalize_kernel<<<BN_TOTAL / 32, 256, 0, stream>>>(
            xh, ybh, maskbuf, coefbuf, mixed);
    } else {
        zero_cnt_kernel<<<1, 64, 0, stream>>>(cnt);
        gate_kernel<false><<<BN_TOTAL / 256, 1024, 0, stream>>>(
            x, Wg, bg, rs, mixed, util, cnt, toklist, scalelist, maskbuf, coefbuf, xh);
        expert_kernel<false><<<dim3(NBLK, E_NUM), 256, 0, stream>>>(
            x, xh, W1, b1, W2, b2, w1T, w2T, mixed, ybh, cnt, toklist, scalelist);
    }
}

// Round 16
// 92.305 us; speedup vs baseline: 1.5633x; 1.0265x over previous
//
#include <hip/hip_runtime.h>
#include <hip/hip_bf16.h>

#define BN_TOTAL   131072      // B*N
#define T_DIM      96
#define E_NUM      8
#define H_DIM      128
#define CAP        131072
#define PTHRESH    0.05f
#define NBLK       64          // expert blocks per expert (512 total = 2/CU)

typedef _Float16 f16x8 __attribute__((ext_vector_type(8)));
typedef _Float16 f16x4 __attribute__((ext_vector_type(4)));
typedef float    f32x4 __attribute__((ext_vector_type(4)));

// ---- workspace layout (bytes) ----
#define OFF_TOK    1024
#define OFF_SCALE  (OFF_TOK   + E_NUM * CAP * 4)
#define OFF_MASK   (OFF_SCALE + E_NUM * CAP * 4)
#define OFF_COEF   (OFF_MASK  + BN_TOTAL * 4)
#define OFF_YBUF   (OFF_COEF  + BN_TOTAL * 4)
#define OFF_XH     (OFF_YBUF + 2 * BN_TOTAL * T_DIM * 2)
#define OFF_W1T    (OFF_XH   + BN_TOTAL * T_DIM * 2)
#define OFF_W2T    (OFF_W1T  + E_NUM * H_DIM * T_DIM * 2)
#define WS_NEED    ((size_t)OFF_YBUF + (size_t)2 * BN_TOTAL * T_DIM * 4)

// toklist entries PACKED: (token<<1)|k ; ybh row id == packed value (< 2*BN).

__global__ void zero_cnt_kernel(int* __restrict__ cnt) {   // non-gather fallback only
    if (threadIdx.x < E_NUM) cnt[threadIdx.x] = 0;
}

// ---- prep: LDS-tiled transpose to f16; block 0 also zeroes cnt[] ----
__global__ __launch_bounds__(256) void prep_kernel(
    const float* __restrict__ W1, const float* __restrict__ W2,
    _Float16* __restrict__ w1T, _Float16* __restrict__ w2T,
    int* __restrict__ cnt)
{
    __shared__ _Float16 tile[128 * 136];
    const int tid = threadIdx.x;
    if (blockIdx.x == 0 && tid < E_NUM) cnt[tid] = 0;
    const bool isW1 = blockIdx.x < 8;
    const int e = blockIdx.x & 7;
    const int R = isW1 ? T_DIM : H_DIM;     // src rows
    const int C = isW1 ? H_DIM : T_DIM;     // src cols
    const int S = isW1 ? 104 : 136;         // LDS row stride (f16)
    const float* src = (isW1 ? W1 : W2) + (size_t)e * T_DIM * H_DIM;
    _Float16* dst = (isW1 ? w1T : w2T) + (size_t)e * T_DIM * H_DIM;

    const int nb = (R >> 2) * (C >> 2);
    for (int b = tid; b < nb; b += 256) {
        const int r4 = b / (C >> 2), c4 = b % (C >> 2);
#pragma unroll
        for (int i = 0; i < 4; ++i) {
            const float4 v = *reinterpret_cast<const float4*>(src + (size_t)(4 * r4 + i) * C + 4 * c4);
            tile[(4 * c4 + 0) * S + 4 * r4 + i] = (_Float16)v.x;
            tile[(4 * c4 + 1) * S + 4 * r4 + i] = (_Float16)v.y;
            tile[(4 * c4 + 2) * S + 4 * r4 + i] = (_Float16)v.z;
            tile[(4 * c4 + 3) * S + 4 * r4 + i] = (_Float16)v.w;
        }
    }
    __syncthreads();
    const int chunks = C * (R >> 3);
    for (int q = tid; q < chunks; q += 256) {
        const int cr = q / (R >> 3), k = q % (R >> 3);
        *reinterpret_cast<f16x8*>(dst + (size_t)cr * R + 8 * k) =
            *reinterpret_cast<const f16x8*>(&tile[cr * S + 8 * k]);
    }
}

// ---- gate: 1024-thread blocks; atomic chain overlapped with global writes ----
template<bool GATHER>
__global__ __launch_bounds__(1024) void gate_kernel(
    const float* __restrict__ x, const float* __restrict__ Wg,
    const float* __restrict__ bg, const float* __restrict__ rs_p,
    float* __restrict__ mixed, float* __restrict__ util,
    int* __restrict__ cnt, int* __restrict__ toklist, float* __restrict__ scalelist,
    int* __restrict__ maskbuf, float* __restrict__ coefbuf, _Float16* __restrict__ xh)
{
    __shared__ float wg_s[E_NUM][T_DIM];
    __shared__ float bg_s[E_NUM];
    __shared__ int wcnt[16][E_NUM];
    __shared__ int wbase[16][E_NUM];

    const int tid = threadIdx.x;
    for (int i = tid; i < E_NUM * T_DIM; i += 1024) wg_s[i / T_DIM][i % T_DIM] = Wg[i];
    if (tid < E_NUM) bg_s[tid] = bg[tid];
    __syncthreads();

    const int g   = tid >> 2;            // token slot 0..255
    const int sub = tid & 3;             // dim quarter
    const int token = blockIdx.x * 256 + g;
    const float* xr_f = x + (size_t)token * T_DIM + sub * 24;

    float4 xv[6];
#pragma unroll
    for (int i = 0; i < 6; ++i) xv[i] = reinterpret_cast<const float4*>(xr_f)[i];

    float logit[E_NUM];
#pragma unroll
    for (int e = 0; e < E_NUM; ++e) logit[e] = 0.0f;
#pragma unroll
    for (int i = 0; i < 6; ++i) {
#pragma unroll
        for (int e = 0; e < E_NUM; ++e) {
            const float4 wv = *reinterpret_cast<const float4*>(&wg_s[e][sub * 24 + 4 * i]);
            logit[e] = fmaf(xv[i].x, wv.x, logit[e]);
            logit[e] = fmaf(xv[i].y, wv.y, logit[e]);
            logit[e] = fmaf(xv[i].z, wv.z, logit[e]);
            logit[e] = fmaf(xv[i].w, wv.w, logit[e]);
        }
    }
#pragma unroll
    for (int e = 0; e < E_NUM; ++e) {
        logit[e] += __shfl_xor(logit[e], 1);
        logit[e] += __shfl_xor(logit[e], 2);
        logit[e] = (logit[e] + bg_s[e]) / 10.0f;
    }

    float mx = logit[0];
#pragma unroll
    for (int e = 1; e < E_NUM; ++e) mx = fmaxf(mx, logit[e]);
    float p[E_NUM]; float s = 0.0f;
#pragma unroll
    for (int e = 0; e < E_NUM; ++e) { p[e] = __expf(logit[e] - mx); s += p[e]; }
    const float inv_s = 1.0f / s;
#pragma unroll
    for (int e = 0; e < E_NUM; ++e) p[e] *= inv_s;

    int i0 = 0; float p0 = p[0];
#pragma unroll
    for (int e = 1; e < E_NUM; ++e) { if (p[e] > p0) { p0 = p[e]; i0 = e; } }
    int i1 = -1; float p1 = -1.0f;
#pragma unroll
    for (int e = 0; e < E_NUM; ++e) { if (e != i0 && p[e] > p1) { p1 = p[e]; i1 = e; } }

    const float denom0 = p0 + p1 + 1e-12f;
    const float w0 = p0 / denom0, w1 = p1 / denom0;
    const bool m0 = (w0 >= PTHRESH), m1 = (w1 >= PTHRESH);
    const float sumw = w0 + w1;
    const float denom1 = fmaxf(sumw, 1e-12f);
    const float wn0 = w0 / denom1, wn1 = w1 / denom1;
    const float rs = *rs_p;
    const float coef = rs * (wn0 + wn1);
    const bool lead = (sub == 0);

    // ---- ballot + per-wave counts FIRST (so the atomic can issue early) ----
    const int lane = tid & 63;
    const int wv_id = tid >> 6;          // 0..15
    const unsigned long long lt = (1ULL << lane) - 1ULL;

    int wcnt_mine = 0, offA = 0, offB = 0;
#pragma unroll
    for (int e = 0; e < E_NUM; ++e) {
        const unsigned long long A = __ballot(lead && m0 && (i0 == e));
        const unsigned long long B = __ballot(lead && m1 && (i1 == e));
        const int na = __popcll(A), nb = __popcll(B);
        if (lane == e) wcnt_mine = na + nb;
        if (lead && m0 && (i0 == e)) offA = __popcll(A & lt);
        if (lead && m1 && (i1 == e)) offB = na + __popcll(B & lt);
    }
    if (lane < E_NUM) wcnt[wv_id][lane] = wcnt_mine;
    __syncthreads();

    // 8 threads issue the device-serialized atomic; result consumed AFTER the
    // overlap region below, so the chain hides under the global writes.
    int run = 0, c[16];
    if (tid < E_NUM) {
        int tot = 0;
#pragma unroll
        for (int w = 0; w < 16; ++w) { c[w] = wcnt[w][tid]; tot += c[w]; }
        run = atomicAdd(&cnt[tid], tot);          // issued; result needed later
    }

    // ---- overlap region: all waves stream xh/util/coef/mask ----
    if (GATHER) {
        _Float16* xr = xh + (size_t)token * T_DIM + sub * 24;
#pragma unroll
        for (int i = 0; i < 6; ++i) {
            f16x4 h4;
            h4[0] = (_Float16)xv[i].x; h4[1] = (_Float16)xv[i].y;
            h4[2] = (_Float16)xv[i].z; h4[3] = (_Float16)xv[i].w;
            reinterpret_cast<f16x4*>(xr)[i] = h4;
        }
        if (lead) { coefbuf[token] = coef; maskbuf[token] = (m0 ? 1 : 0) | (m1 ? 2 : 0); }
    } else {
        float* mr = mixed + (size_t)token * T_DIM + sub * 24;
#pragma unroll
        for (int i = 0; i < 6; ++i)
            reinterpret_cast<float4*>(mr)[i] =
                make_float4(coef * xv[i].x, coef * xv[i].y, coef * xv[i].z, coef * xv[i].w);
    }
    if (lead) {
        float u[E_NUM];
#pragma unroll
        for (int e = 0; e < E_NUM; ++e)
            u[e] = (((e == i0) && m0) || ((e == i1) && m1)) ? 1.0f : 0.0f;
        float4* u4 = reinterpret_cast<float4*>(util + (size_t)token * E_NUM);
        u4[0] = make_float4(u[0], u[1], u[2], u[3]);
        u4[1] = make_float4(u[4], u[5], u[6], u[7]);
    }

    // consume the atomic result, publish wave bases
    if (tid < E_NUM) {
#pragma unroll
        for (int w = 0; w < 16; ++w) { wbase[w][tid] = run; run += c[w]; }
    }
    __syncthreads();

    if (lead && m0) {
        const int pos = wbase[wv_id][i0] + offA;
        toklist[i0 * CAP + pos] = (token << 1);
        scalelist[i0 * CAP + pos] = rs * wn0;
    }
    if (lead && m1) {
        const int pos = wbase[wv_id][i1] + offB;
        toklist[i1 * CAP + pos] = (token << 1) | 1;
        scalelist[i1 * CAP + pos] = rs * wn1;
    }
}

// ---------------- MFMA expert kernel: software-pipelined gather ----------------
// r15 evidence: 12K cy/iter vs ~1K compute -> exposed tl->xh latency chain,
// nothing prefetched, 2 waves/SIMD can't hide HBM. Pipeline one iteration
// ahead: meta(i+1) issued at loop top (hides under phase-1), xf(i+1) issued
// after phase-1 (hides under barrier+phase-2+epilogue).
template<bool GATHER>
__global__ __launch_bounds__(256, 2) void expert_kernel(
    const float* __restrict__ x, const _Float16* __restrict__ xh,
    const float* __restrict__ W1, const float* __restrict__ b1,
    const float* __restrict__ W2, const float* __restrict__ b2,
    const _Float16* __restrict__ w1T, const _Float16* __restrict__ w2T,
    float* __restrict__ mixed, _Float16* __restrict__ ybh,
    const int* __restrict__ cnt, const int* __restrict__ toklist,
    const float* __restrict__ scalelist)
{
    __shared__ __align__(16) _Float16 Hs[2][64 * 136];

    const int e = blockIdx.y;
    const int count = cnt[e];
    if ((int)blockIdx.x * 64 >= count) return;

    const int tid  = threadIdx.x;
    const int w    = tid >> 6;
    const int lane = tid & 63;
    const int lm   = lane & 15;
    const int lg4  = lane >> 4;
    const int mhalf = w & 1;
    const int nhalf = w >> 1;

    const int*   tl = toklist   + (size_t)e * CAP;
    const float* sl = scalelist + (size_t)e * CAP;

    f16x8 w1f[3][4];
    {
        const _Float16* w1e = w1T + (size_t)e * H_DIM * T_DIM;
        const float*    gW1 = W1  + (size_t)e * T_DIM * H_DIM;
#pragma unroll
        for (int ks = 0; ks < 3; ++ks)
#pragma unroll
            for (int n = 0; n < 4; ++n) {
                const int h = nhalf * 64 + n * 16 + lm;
                if (GATHER) {
                    w1f[ks][n] = *reinterpret_cast<const f16x8*>(
                        w1e + (size_t)h * T_DIM + ks * 32 + lg4 * 8);
                } else {
                    f16x8 v;
#pragma unroll
                    for (int j = 0; j < 8; ++j)
                        v[j] = (_Float16)gW1[(size_t)(ks * 32 + lg4 * 8 + j) * H_DIM + h];
                    w1f[ks][n] = v;
                }
            }
    }
    f16x8 w2f[4][3];
    {
        const _Float16* w2e = w2T + (size_t)e * H_DIM * T_DIM;
        const float*    gW2 = W2  + (size_t)e * H_DIM * T_DIM;
#pragma unroll
        for (int ks = 0; ks < 4; ++ks)
#pragma unroll
            for (int n = 0; n < 3; ++n) {
                const int t = nhalf * 48 + n * 16 + lm;
                if (GATHER) {
                    w2f[ks][n] = *reinterpret_cast<const f16x8*>(
                        w2e + (size_t)t * H_DIM + ks * 32 + lg4 * 8);
                } else {
                    f16x8 v;
#pragma unroll
                    for (int j = 0; j < 8; ++j)
                        v[j] = (_Float16)gW2[(size_t)(ks * 32 + lg4 * 8 + j) * T_DIM + t];
                    w2f[ks][n] = v;
                }
            }
    }
    float4 b1v[4], b2v[3];
#pragma unroll
    for (int n = 0; n < 4; ++n)
        b1v[n] = *reinterpret_cast<const float4*>(b1 + e * H_DIM + nhalf * 64 + n * 16 + lg4 * 4);
#pragma unroll
    for (int n = 0; n < 3; ++n)
        b2v[n] = *reinterpret_cast<const float4*>(b2 + e * T_DIM + nhalf * 48 + n * 16 + lg4 * 4);

    const int stride = NBLK * 64;
    int t0 = blockIdx.x * 64;

    // ---- prologue: meta + xf for the first tile ----
    int packedi[2]; float sci[2]; bool val[2];
    {
        const int nt = min(64, count - t0);
#pragma unroll
        for (int mt = 0; mt < 2; ++mt) {
            const int slot = (mhalf * 2 + mt) * 16 + lm;
            val[mt] = slot < nt;
            const int gi = t0 + (val[mt] ? slot : 0);
            packedi[mt] = tl[gi];
            sci[mt] = sl[gi];
        }
    }
    f16x8 xf[2][3];
#pragma unroll
    for (int mt = 0; mt < 2; ++mt)
#pragma unroll
        for (int ks = 0; ks < 3; ++ks) {
            if (GATHER) {
                xf[mt][ks] = *reinterpret_cast<const f16x8*>(
                    xh + (size_t)(packedi[mt] >> 1) * T_DIM + ks * 32 + lg4 * 8);
            } else {
                const float* xp = x + (size_t)(packedi[mt] >> 1) * T_DIM + ks * 32 + lg4 * 8;
                f16x8 v;
#pragma unroll
                for (int j = 0; j < 8; ++j) v[j] = (_Float16)xp[j];
                xf[mt][ks] = v;
            }
        }

    int buf = 0;
    while (t0 < count) {
        const int t1 = t0 + stride;
        const bool have_next = t1 < count;

        // prefetch next tile's meta (latency hides under phase-1)
        int pk2[2]; float sc2[2]; bool v2[2];
        if (have_next) {
            const int nt2 = min(64, count - t1);
#pragma unroll
            for (int mt = 0; mt < 2; ++mt) {
                const int slot = (mhalf * 2 + mt) * 16 + lm;
                v2[mt] = slot < nt2;
                const int gi = t1 + (v2[mt] ? slot : 0);
                pk2[mt] = tl[gi];
                sc2[mt] = sl[gi];
            }
        }

        // phase 1: Ht = W1^T @ X^T
        f32x4 acc1[2][4];
#pragma unroll
        for (int mt = 0; mt < 2; ++mt)
#pragma unroll
            for (int n = 0; n < 4; ++n) acc1[mt][n] = f32x4{0.f, 0.f, 0.f, 0.f};
#pragma unroll
        for (int ks = 0; ks < 3; ++ks)
#pragma unroll
            for (int n = 0; n < 4; ++n) {
                acc1[0][n] = __builtin_amdgcn_mfma_f32_16x16x32_f16(w1f[ks][n], xf[0][ks], acc1[0][n], 0, 0, 0);
                acc1[1][n] = __builtin_amdgcn_mfma_f32_16x16x32_f16(w1f[ks][n], xf[1][ks], acc1[1][n], 0, 0, 0);
            }

        // prefetch next tile's xf (hides under LDS write + barrier + phase-2)
        f16x8 xf2[2][3];
        if (have_next) {
#pragma unroll
            for (int mt = 0; mt < 2; ++mt)
#pragma unroll
                for (int ks = 0; ks < 3; ++ks) {
                    if (GATHER) {
                        xf2[mt][ks] = *reinterpret_cast<const f16x8*>(
                            xh + (size_t)(pk2[mt] >> 1) * T_DIM + ks * 32 + lg4 * 8);
                    } else {
                        const float* xp = x + (size_t)(pk2[mt] >> 1) * T_DIM + ks * 32 + lg4 * 8;
                        f16x8 v;
#pragma unroll
                        for (int j = 0; j < 8; ++j) v[j] = (_Float16)xp[j];
                        xf2[mt][ks] = v;
                    }
                }
        }

        // bias+relu -> Hs[buf]
#pragma unroll
        for (int mt = 0; mt < 2; ++mt) {
            const int tok = (mhalf * 2 + mt) * 16 + lm;
#pragma unroll
            for (int n = 0; n < 4; ++n) {
                const float* bb = reinterpret_cast<const float*>(&b1v[n]);
                f16x4 hv;
#pragma unroll
                for (int r = 0; r < 4; ++r)
                    hv[r] = (_Float16)fmaxf(acc1[mt][n][r] + bb[r], 0.0f);
                *reinterpret_cast<f16x4*>(&Hs[buf][tok * 136 + nhalf * 64 + n * 16 + lg4 * 4]) = hv;
            }
        }
        __syncthreads();

        // phase 2: Yt = W2^T @ H^T
        f32x4 acc2[2][3];
#pragma unroll
        for (int mt = 0; mt < 2; ++mt)
#pragma unroll
            for (int n = 0; n < 3; ++n) acc2[mt][n] = f32x4{0.f, 0.f, 0.f, 0.f};
#pragma unroll
        for (int ks = 0; ks < 4; ++ks) {
            const f16x8 hf0 = *reinterpret_cast<const f16x8*>(
                &Hs[buf][((mhalf * 2 + 0) * 16 + lm) * 136 + ks * 32 + lg4 * 8]);
            const f16x8 hf1 = *reinterpret_cast<const f16x8*>(
                &Hs[buf][((mhalf * 2 + 1) * 16 + lm) * 136 + ks * 32 + lg4 * 8]);
#pragma unroll
            for (int n = 0; n < 3; ++n) {
                acc2[0][n] = __builtin_amdgcn_mfma_f32_16x16x32_f16(w2f[ks][n], hf0, acc2[0][n], 0, 0, 0);
                acc2[1][n] = __builtin_amdgcn_mfma_f32_16x16x32_f16(w2f[ks][n], hf1, acc2[1][n], 0, 0, 0);
            }
        }

        // epilogue: ybh[packed][t] = f16( sc * (y + b2) )
#pragma unroll
        for (int mt = 0; mt < 2; ++mt) {
            if (val[mt]) {
#pragma unroll
                for (int n = 0; n < 3; ++n) {
                    const float* bb = reinterpret_cast<const float*>(&b2v[n]);
                    f16x4 yv;
#pragma unroll
                    for (int r = 0; r < 4; ++r)
                        yv[r] = (_Float16)(sci[mt] * (acc2[mt][n][r] + bb[r]));
                    if (GATHER) {
                        *reinterpret_cast<f16x4*>(
                            ybh + (size_t)packedi[mt] * T_DIM + nhalf * 48 + n * 16 + lg4 * 4) = yv;
                    } else {
#pragma unroll
                        for (int r = 0; r < 4; ++r)
                            atomicAdd(&mixed[(size_t)(packedi[mt] >> 1) * T_DIM +
                                             nhalf * 48 + n * 16 + lg4 * 4 + r], (float)yv[r]);
                    }
                }
            }
        }

        // rotate pipeline state
#pragma unroll
        for (int mt = 0; mt < 2; ++mt) {
            packedi[mt] = pk2[mt]; sci[mt] = sc2[mt]; val[mt] = v2[mt];
#pragma unroll
            for (int ks = 0; ks < 3; ++ks) xf[mt][ks] = xf2[mt][ks];
        }
        t0 = t1;
        buf ^= 1;
    }
}

// mixed[tok] = coef*xh[tok] + (mask&1 ? ybh[2t] : 0) + (mask&2 ? ybh[2t+1] : 0)
__global__ __launch_bounds__(256) void finalize_kernel(
    const _Float16* __restrict__ xh, const _Float16* __restrict__ ybh,
    const int* __restrict__ maskbuf, const float* __restrict__ coefbuf,
    float* __restrict__ mixed)
{
    const int tid = threadIdx.x;
    const int token = blockIdx.x * 32 + (tid >> 3);
    const int seg = (tid & 7) * 12;

    const float coef = coefbuf[token];
    const int mask = maskbuf[token];

    const f16x4* xs = reinterpret_cast<const f16x4*>(xh + (size_t)token * T_DIM + seg);
    float4* od = reinterpret_cast<float4*>(mixed + (size_t)token * T_DIM + seg);

    float4 r[3];
#pragma unroll
    for (int q = 0; q < 3; ++q) {
        const f16x4 xv = xs[q];
        r[q] = make_float4(coef * (float)xv[0], coef * (float)xv[1],
                           coef * (float)xv[2], coef * (float)xv[3]);
    }
    if (mask & 1) {
        const f16x4* ys = reinterpret_cast<const f16x4*>(ybh + (size_t)(2 * token) * T_DIM + seg);
#pragma unroll
        for (int q = 0; q < 3; ++q) {
            const f16x4 yv = ys[q];
            r[q].x += (float)yv[0]; r[q].y += (float)yv[1];
            r[q].z += (float)yv[2]; r[q].w += (float)yv[3];
        }
    }
    if (mask & 2) {
        const f16x4* ys = reinterpret_cast<const f16x4*>(ybh + (size_t)(2 * token + 1) * T_DIM + seg);
#pragma unroll
        for (int q = 0; q < 3; ++q) {
            const f16x4 yv = ys[q];
            r[q].x += (float)yv[0]; r[q].y += (float)yv[1];
            r[q].z += (float)yv[2]; r[q].w += (float)yv[3];
        }
    }
#pragma unroll
    for (int q = 0; q < 3; ++q) od[q] = r[q];
}

extern "C" void kernel_launch(void* const* d_in, const int* in_sizes, int n_in,
                              void* d_out, int out_size, void* d_ws, size_t ws_size,
                              hipStream_t stream)
{
    const float* x  = (const float*)d_in[0];
    const float* Wg = (const float*)d_in[1];
    const float* bg = (const float*)d_in[2];
    const float* W1 = (const float*)d_in[3];
    const float* b1 = (const float*)d_in[4];
    const float* W2 = (const float*)d_in[5];
    const float* b2 = (const float*)d_in[6];
    const float* rs = (const float*)d_in[7];

    float* mixed = (float*)d_out;
    float* util  = mixed + (size_t)BN_TOTAL * T_DIM;

    char* ws = (char*)d_ws;
    int*      cnt       = (int*)ws;
    int*      toklist   = (int*)(ws + OFF_TOK);
    float*    scalelist = (float*)(ws + OFF_SCALE);
    int*      maskbuf   = (int*)(ws + OFF_MASK);
    float*    coefbuf   = (float*)(ws + OFF_COEF);
    _Float16* ybh       = (_Float16*)(ws + OFF_YBUF);
    _Float16* xh        = (_Float16*)(ws + OFF_XH);
    _Float16* w1T       = (_Float16*)(ws + OFF_W1T);
    _Float16* w2T       = (_Float16*)(ws + OFF_W2T);

    const bool gather = (ws_size >= WS_NEED);

    if (gather) {
        prep_kernel<<<16, 256, 0, stream>>>(W1, W2, w1T, w2T, cnt);
        gate_kernel<true><<<BN_TOTAL / 256, 1024, 0, stream>>>(
            x, Wg, bg, rs, mixed, util, cnt, toklist, scalelist, maskbuf, coefbuf, xh);
        expert_kernel<true><<<dim3(NBLK, E_NUM), 256, 0, stream>>>(
            x, xh, W1, b1, W2, b2, w1T, w2T, mixed, ybh, cnt, toklist, scalelist);
        finalize_kernel<<<BN_TOTAL / 32, 256, 0, stream>>>(
            xh, ybh, maskbuf, coefbuf, mixed);
    } else {
        zero_cnt_kernel<<<1, 64, 0, stream>>>(cnt);
        gate_kernel<false><<<BN_TOTAL / 256, 1024, 0, stream>>>(
            x, Wg, bg, rs, mixed, util, cnt, toklist, scalelist, maskbuf, coefbuf, xh);
        expert_kernel<false><<<dim3(NBLK, E_NUM), 256, 0, stream>>>(
            x, xh, W1, b1, W2, b2, w1T, w2T, mixed, ybh, cnt, toklist, scalelist);
    }
}